// Round 7
// baseline (62.618 us; speedup 1.0000x reference)
//
#include <hip/hip_runtime.h>
#include <hip/hip_bf16.h>

typedef __attribute__((ext_vector_type(8))) short    s8v;  // bf16x8 MFMA operand
typedef __attribute__((ext_vector_type(4))) float    f4v;  // fp32x4 MFMA C/D
typedef __attribute__((ext_vector_type(4))) unsigned u4v;

__device__ __forceinline__ unsigned short bfu(float x){
  union { __hip_bfloat16 h; unsigned short u; } cv;
  cv.h = __float2bfloat16(x);
  return cv.u;
}
__device__ __forceinline__ unsigned pkbf(float lo, float hi){
  return (unsigned)bfu(lo) | ((unsigned)bfu(hi) << 16);
}
__device__ __forceinline__ s8v mkfrag(unsigned a, unsigned b, unsigned c_, unsigned d){
  u4v u = {a, b, c_, d};
  return __builtin_bit_cast(s8v, u);
}
__device__ __forceinline__ f4v MM(s8v a, s8v b, f4v acc){
  return __builtin_amdgcn_mfma_f32_16x16x32_bf16(a, b, acc, 0, 0, 0);
}

// Opaque-value pins: the compiler cannot rematerialize these, so the one-time
// weight fragments stay register-resident across the group loop (R6 lesson:
// launch_bounds alone doesn't stop remat; VGPR stayed 88 with ~900 extra
// VALU/pair of reload+repack).
__device__ __forceinline__ void keep(s8v &x){ asm volatile("" : "+v"(x)); }
__device__ __forceinline__ void keep(f4v &x){ asm volatile("" : "+v"(x)); }
__device__ __forceinline__ void keep(float &x){ asm volatile("" : "+v"(x)); }

// Packed D-quad: p0 = (row 4g, 4g+1), p1 = (row 4g+2, 4g+3) at col c.
struct Pk { unsigned p0, p1; };
template<bool RELU>
__device__ __forceinline__ Pk mkpk(f4v d){
  float a = d[0], b = d[1], c_ = d[2], e = d[3];
  if (RELU){ a = fmaxf(a,0.f); b = fmaxf(b,0.f); c_ = fmaxf(c_,0.f); e = fmaxf(e,0.f); }
  Pk r; r.p0 = pkbf(a, b); r.p1 = pkbf(c_, e); return r;
}

// ZERO-SHUFFLE CHAINING (verified R5): D-quad fed straight into B-frag regs
// (0,1) puts feature f=4g+r at k=8g+r; A is loaded with the same row
// permutation, so no cross-lane movement between MLP stages.
__device__ __forceinline__ s8v bfragK16(Pk x){ return mkfrag(x.p0, x.p1, 0u, 0u); }
__device__ __forceinline__ s8v bfragCat(Pk x, Pk y){ return mkfrag(x.p0, x.p1, y.p0, y.p1); }

__device__ __forceinline__ s8v loadA16(const float* __restrict__ W, int K, int c, int g,
                                       float scale = 1.0f){
  int r0 = 4*g;
  unsigned u0 = pkbf(r0+0<K ? W[(r0+0)*16+c]*scale : 0.f, r0+1<K ? W[(r0+1)*16+c]*scale : 0.f);
  unsigned u1 = pkbf(r0+2<K ? W[(r0+2)*16+c]*scale : 0.f, r0+3<K ? W[(r0+3)*16+c]*scale : 0.f);
  return mkfrag(u0, u1, 0u, 0u);
}
__device__ __forceinline__ s8v loadA32(const float* __restrict__ W, int c, int g){
  int r0 = 4*g;
  unsigned u0 = pkbf(W[(r0+0)*16+c],      W[(r0+1)*16+c]);
  unsigned u1 = pkbf(W[(r0+2)*16+c],      W[(r0+3)*16+c]);
  unsigned u2 = pkbf(W[(16+r0+0)*16+c],   W[(16+r0+1)*16+c]);
  unsigned u3 = pkbf(W[(16+r0+2)*16+c],   W[(16+r0+3)*16+c]);
  return mkfrag(u0, u1, u2, u3);
}
__device__ __forceinline__ f4v ldb(const float* __restrict__ b, int g){
  f4v v; v[0] = b[4*g+0]; v[1] = b[4*g+1]; v[2] = b[4*g+2]; v[3] = b[4*g+3];
  return v;
}

// permlane swaps for the final 4-quarter reduction only (VALU, no LDS).
__device__ __forceinline__ void pl32(unsigned &a, unsigned &b){
  asm("v_permlane32_swap_b32 %0, %1" : "+v"(a), "+v"(b));
}
__device__ __forceinline__ void pl16(unsigned &a, unsigned &b){
  asm("v_permlane16_swap_b32 %0, %1" : "+v"(a), "+v"(b));
}
__device__ __forceinline__ float qsum(float part){
  unsigned pu = __builtin_bit_cast(unsigned, part), pv = pu;
  pl16(pu, pv);
  part = __builtin_bit_cast(float, pu) + __builtin_bit_cast(float, pv);
  pu = __builtin_bit_cast(unsigned, part); pv = pu;
  pl32(pu, pv);
  return __builtin_bit_cast(float, pu) + __builtin_bit_cast(float, pv);
}

__global__ void __launch_bounds__(256, 2) egnn_pin(
    const float* __restrict__ nf,   const float* __restrict__ dist,
    const float* __restrict__ dz,   const float* __restrict__ s2p,
    const float* __restrict__ neW1, const float* __restrict__ neb1,
    const float* __restrict__ neW2, const float* __restrict__ neb2,
    const float* __restrict__ eeW1, const float* __restrict__ eeb1,
    const float* __restrict__ eeW2, const float* __restrict__ eeb2,
    const float* __restrict__ msgW1, const float* __restrict__ msgb1,
    const float* __restrict__ msgW2, const float* __restrict__ msgb2,
    const float* __restrict__ updW1, const float* __restrict__ updb1,
    const float* __restrict__ updW2, const float* __restrict__ updb2,
    const float* __restrict__ clsW1, const float* __restrict__ clsb1,
    const float* __restrict__ clsW2, const float* __restrict__ clsb2,
    float* __restrict__ out, int B, int npairs, int nwaves)
{
  const int lane = threadIdx.x & 63;
  const int c = lane & 15;
  const int g = lane >> 4;
  const int gwave = blockIdx.x * (blockDim.x >> 6) + (threadIdx.x >> 6);

  // ---- one-time per-wave weight fragments & bias C-inits, then PIN them ----
  s8v aNe1 = loadA16(neW1, 2, c, g);
  s8v aNe2 = loadA16(neW2, 16, c, g);
  s8v aEe1 = loadA16(eeW1, 3, c, g);
  s8v aEe2 = loadA16(eeW2, 16, c, g);
  s8v aCl  = loadA16(clsW1, 16, c, g, 0.5f);   // fold the node-mean 0.5
  s8v aM0[2], aM1[2], aM2[2], aU1[2], aU2[2];
  f4v bM1[2], bM2[2], bU1[2], bU2[2];
  #pragma unroll
  for (int l = 0; l < 2; ++l){
    aM0[l] = loadA32(msgW1 + l*768, c, g);            // concat rows 0..31
    aM1[l] = loadA16(msgW1 + l*768 + 512, 16, c, g);  // rows 32..47 (ee)
    aM2[l] = loadA16(msgW2 + l*256, 16, c, g);
    aU1[l] = loadA32(updW1 + l*512, c, g);            // rows 0..15 h, 16..31 msg
    aU2[l] = loadA16(updW2 + l*256, 16, c, g);
    bM1[l] = ldb(msgb1 + l*16, g);
    bM2[l] = ldb(msgb2 + l*16, g);
    bU1[l] = ldb(updb1 + l*16, g);
    bU2[l] = ldb(updb2 + l*16, g);
  }
  f4v bNe1 = ldb(neb1,g), bNe2 = ldb(neb2,g), bEe1 = ldb(eeb1,g), bEe2 = ldb(eeb2,g), bCl1 = ldb(clsb1,g);
  float w2a = clsW2[4*g+0], w2b = clsW2[4*g+1], w2c = clsW2[4*g+2], w2d = clsW2[4*g+3];
  const float cb2 = clsb2[0];

  keep(aNe1); keep(aNe2); keep(aEe1); keep(aEe2); keep(aCl);
  #pragma unroll
  for (int l = 0; l < 2; ++l){
    keep(aM0[l]); keep(aM1[l]); keep(aM2[l]); keep(aU1[l]); keep(aU2[l]);
    keep(bM1[l]); keep(bM2[l]); keep(bU1[l]); keep(bU2[l]);
  }
  keep(bNe1); keep(bNe2); keep(bEe1); keep(bEe2); keep(bCl1);
  keep(w2a); keep(w2b); keep(w2c); keep(w2d);

  // ---- 2-group-ILP loop: two independent pipelines share weight regs ----
  #pragma unroll 1
  for (int p = gwave; p < npairs; p += nwaves){
    const int e0A = (2*p)     * 16;
    const int e0B = (2*p + 1) * 16;
    const int eA = min(e0A + c, B-1);
    const int eB = min(e0B + c, B-1);
    const float4 nfA = *reinterpret_cast<const float4*>(nf + (size_t)eA * 4);
    const float4 nfB = *reinterpret_cast<const float4*>(nf + (size_t)eB * 4);
    const float diA = dist[eA], zzA = dz[eA], spA = s2p[eA];
    const float diB = dist[eB], zzB = dz[eB], spB = s2p[eB];

    // ---- embeddings (interleaved A/B) ----
    s8v bA0 = mkfrag(g==0 ? pkbf(nfA.x, nfA.y) : 0u, 0u, 0u, 0u);
    s8v bB0 = mkfrag(g==0 ? pkbf(nfB.x, nfB.y) : 0u, 0u, 0u, 0u);
    s8v bA1 = mkfrag(g==0 ? pkbf(nfA.z, nfA.w) : 0u, 0u, 0u, 0u);
    s8v bB1 = mkfrag(g==0 ? pkbf(nfB.z, nfB.w) : 0u, 0u, 0u, 0u);
    s8v beA = mkfrag(g==0 ? pkbf(diA, zzA) : 0u, g==0 ? pkbf(spA, 0.f) : 0u, 0u, 0u);
    s8v beB = mkfrag(g==0 ? pkbf(diB, zzB) : 0u, g==0 ? pkbf(spB, 0.f) : 0u, 0u, 0u);
    f4v tA0 = MM(aNe1, bA0, bNe1);   f4v tB0 = MM(aNe1, bB0, bNe1);
    f4v tA1 = MM(aNe1, bA1, bNe1);   f4v tB1 = MM(aNe1, bB1, bNe1);
    f4v teA = MM(aEe1, beA, bEe1);   f4v teB = MM(aEe1, beB, bEe1);
    f4v hA0 = MM(aNe2, bfragK16(mkpk<true>(tA0)), bNe2);
    f4v hB0 = MM(aNe2, bfragK16(mkpk<true>(tB0)), bNe2);
    f4v hA1 = MM(aNe2, bfragK16(mkpk<true>(tA1)), bNe2);
    f4v hB1 = MM(aNe2, bfragK16(mkpk<true>(tB1)), bNe2);
    f4v eeA = MM(aEe2, bfragK16(mkpk<true>(teA)), bEe2);
    f4v eeB = MM(aEe2, bfragK16(mkpk<true>(teB)), bEe2);
    const s8v efA = bfragK16(mkpk<false>(eeA));
    const s8v efB = bfragK16(mkpk<false>(eeB));

    // ---- message-passing layers ----
    #pragma unroll
    for (int l = 0; l < 2; ++l){
      Pk pA0 = mkpk<false>(hA0), pA1 = mkpk<false>(hA1);
      Pk pB0 = mkpk<false>(hB0), pB1 = mkpk<false>(hB1);
      f4v eCA = MM(aM1[l], efA, bM1[l]);
      f4v eCB = MM(aM1[l], efB, bM1[l]);
      f4v mA0 = MM(aM0[l], bfragCat(pA0, pA1), eCA);
      f4v mB0 = MM(aM0[l], bfragCat(pB0, pB1), eCB);
      f4v mA1 = MM(aM0[l], bfragCat(pA1, pA0), eCA);
      f4v mB1 = MM(aM0[l], bfragCat(pB1, pB0), eCB);
      f4v gA0 = MM(aM2[l], bfragK16(mkpk<true>(mA0)), bM2[l]);
      f4v gB0 = MM(aM2[l], bfragK16(mkpk<true>(mB0)), bM2[l]);
      f4v gA1 = MM(aM2[l], bfragK16(mkpk<true>(mA1)), bM2[l]);
      f4v gB1 = MM(aM2[l], bfragK16(mkpk<true>(mB1)), bM2[l]);
      f4v uA0 = MM(aU1[l], bfragCat(pA0, mkpk<false>(gA0)), bU1[l]);
      f4v uB0 = MM(aU1[l], bfragCat(pB0, mkpk<false>(gB0)), bU1[l]);
      f4v uA1 = MM(aU1[l], bfragCat(pA1, mkpk<false>(gA1)), bU1[l]);
      f4v uB1 = MM(aU1[l], bfragCat(pB1, mkpk<false>(gB1)), bU1[l]);
      hA0 = hA0 + MM(aU2[l], bfragK16(mkpk<true>(uA0)), bU2[l]);
      hB0 = hB0 + MM(aU2[l], bfragK16(mkpk<true>(uB0)), bU2[l]);
      hA1 = hA1 + MM(aU2[l], bfragK16(mkpk<true>(uA1)), bU2[l]);
      hB1 = hB1 + MM(aU2[l], bfragK16(mkpk<true>(uB1)), bU2[l]);
    }

    // ---- classifier (0.5 pre-folded into aCl) ----
    f4v tcA = MM(aCl, bfragK16(mkpk<false>(hA0 + hA1)), bCl1);
    f4v tcB = MM(aCl, bfragK16(mkpk<false>(hB0 + hB1)), bCl1);
    float prA = fmaxf(tcA[0],0.f)*w2a + fmaxf(tcA[1],0.f)*w2b
              + fmaxf(tcA[2],0.f)*w2c + fmaxf(tcA[3],0.f)*w2d;
    float prB = fmaxf(tcB[0],0.f)*w2a + fmaxf(tcB[1],0.f)*w2b
              + fmaxf(tcB[2],0.f)*w2c + fmaxf(tcB[3],0.f)*w2d;
    prA = qsum(prA);
    prB = qsum(prB);
    if (lane < 16){
      if (e0A + c < B) out[e0A + c] = prA + cb2;
      if (e0B + c < B) out[e0B + c] = prB + cb2;
    }
  }
}

extern "C" void kernel_launch(void* const* d_in, const int* in_sizes, int n_in,
                              void* d_out, int out_size, void* d_ws, size_t ws_size,
                              hipStream_t stream) {
  const float* nf    = (const float*)d_in[0];
  const float* dist  = (const float*)d_in[1];
  const float* dz    = (const float*)d_in[2];
  const float* s2p   = (const float*)d_in[3];
  const float* neW1  = (const float*)d_in[4];
  const float* neb1  = (const float*)d_in[5];
  const float* neW2  = (const float*)d_in[6];
  const float* neb2  = (const float*)d_in[7];
  const float* eeW1  = (const float*)d_in[8];
  const float* eeb1  = (const float*)d_in[9];
  const float* eeW2  = (const float*)d_in[10];
  const float* eeb2  = (const float*)d_in[11];
  const float* msgW1 = (const float*)d_in[12];
  const float* msgb1 = (const float*)d_in[13];
  const float* msgW2 = (const float*)d_in[14];
  const float* msgb2 = (const float*)d_in[15];
  const float* updW1 = (const float*)d_in[16];
  const float* updb1 = (const float*)d_in[17];
  const float* updW2 = (const float*)d_in[18];
  const float* updb2 = (const float*)d_in[19];
  const float* clsW1 = (const float*)d_in[20];
  const float* clsb1 = (const float*)d_in[21];
  const float* clsW2 = (const float*)d_in[22];
  const float* clsb2 = (const float*)d_in[23];

  const int B = in_sizes[1];
  const int ngroups = (B + 15) / 16;
  const int npairs  = (ngroups + 1) / 2;
  int blocks = 2048;
  const int wpb = 256 / 64;
  if (blocks * wpb > npairs) blocks = (npairs + wpb - 1) / wpb;
  const int nwaves = blocks * wpb;

  egnn_pin<<<blocks, 256, 0, stream>>>(
      nf, dist, dz, s2p,
      neW1, neb1, neW2, neb2,
      eeW1, eeb1, eeW2, eeb2,
      msgW1, msgb1, msgW2, msgb2,
      updW1, updb1, updW2, updb2,
      clsW1, clsb1, clsW2, clsb2,
      (float*)d_out, B, npairs, nwaves);
}